// Round 3
// baseline (271.373 us; speedup 1.0000x reference)
//
#include <hip/hip_runtime.h>
#include <hip/hip_bf16.h>

// out[c,n,o] = sum_i x[c,n,i] * W[model_idx[c],i,o] + B[int(t[c]*31),o]
// x[64,2048,256] f32, t[64] f32, model_idx[64] i32, W[64,256,256] f32,
// B[32,256] f32, out f32.  (Round-2 NaN showed inputs are fp32, matching the
// reference dtypes — the 2% threshold exists to permit bf16 internal math.)
//
// Per block: one channel, 256 rows (2 x 128-row tiles), 128 cols.
// W panel transposed+converted to bf16 LDS once per block; X tiles staged
// fp32->bf16 through registers each K-step; mfma_f32_16x16x32_bf16 core.

#define M_PTS 2048
#define K_DIM 256
#define N_DIM 256
#define BT_STRIDE 264  // 256 + 8: (264*2)%16==0 keeps b128 alignment, breaks pow2 banks

typedef float floatx4 __attribute__((ext_vector_type(4)));
typedef __bf16 bf16x4 __attribute__((ext_vector_type(4)));
typedef __bf16 bf16x8 __attribute__((ext_vector_type(8)));

__device__ __forceinline__ __bf16 cvt_bf16(float f) {
  // round-to-nearest-even f32 -> bf16 (finite inputs), branch-free
  unsigned u = __builtin_bit_cast(unsigned, f);
  unsigned r = (u + 0x7FFFu + ((u >> 16) & 1u)) >> 16;
  return __builtin_bit_cast(__bf16, (unsigned short)r);
}

__global__ __launch_bounds__(256) void fused_k(
    const float* __restrict__ X, const float* __restrict__ T,
    const int* __restrict__ MI, const float* __restrict__ W,
    const float* __restrict__ Bb, float* __restrict__ Out) {
  __shared__ __bf16 As[128 * 32];        // X tile [m=128][k=32]
  __shared__ __bf16 Bt[128 * BT_STRIDE]; // W^T panel [n=128][k=256]

  const int bid = blockIdx.x;      // 1024 blocks
  const int c   = bid >> 4;        // channel (64)
  const int mg  = (bid >> 1) & 7;  // 256-row m-group (8)
  const int nt  = bid & 1;         // n-half (2); twins adjacent -> X L2/L3 reuse
  const int n0  = nt * 128;

  const float* __restrict__ Xc = X + (size_t)c * (M_PTS * K_DIM);
  const float* __restrict__ Wc = W + (size_t)MI[c] * (K_DIM * N_DIM);

  const int tid  = threadIdx.x;
  const int lane = tid & 63;
  const int w    = tid >> 6;
  const int wm   = w & 1;      // 2x2 wave grid
  const int wn   = w >> 1;
  const int r    = lane & 15;  // fragment row/col
  const int kg   = lane >> 4;  // k-group 0..3

  // ---- one-time: Bt[n][k] = bf16(Wc[k][n0+n]) ----------------------------
  // lanes take consecutive n -> each global read is a full 256B segment
  {
    const int n  = tid & 127;
    const int kq = tid >> 7;  // k-half
    const float* __restrict__ src = Wc + (size_t)(kq * 128) * N_DIM + n0 + n;
    __bf16* __restrict__ dst = &Bt[n * BT_STRIDE + kq * 128];
#pragma unroll 4
    for (int u = 0; u < 32; ++u) {
      bf16x4 v;
      v.x = cvt_bf16(src[(size_t)(u * 4 + 0) * N_DIM]);
      v.y = cvt_bf16(src[(size_t)(u * 4 + 1) * N_DIM]);
      v.z = cvt_bf16(src[(size_t)(u * 4 + 2) * N_DIM]);
      v.w = cvt_bf16(src[(size_t)(u * 4 + 3) * N_DIM]);
      *(bf16x4*)&dst[u * 4] = v;  // 8B store, k-contiguous
    }
  }

  // ---- As staging mapping: thread -> (row, k-half) -----------------------
  const int sm  = tid >> 1;         // row 0..127
  const int skh = (tid & 1) * 16;   // k offset 0/16
  const float* __restrict__ xrow = Xc + skh;
  __bf16* __restrict__ adst = &As[sm * 32 + skh];

  // ---- bias (fp32, exact): idx = trunc(t[c]*31) --------------------------
  int bidx = (int)(T[c] * 31.0f);
  bidx = bidx < 0 ? 0 : (bidx > 31 ? 31 : bidx);
  const float* __restrict__ brow = Bb + bidx * N_DIM + n0 + wn * 64;
  float bv[4];
#pragma unroll
  for (int j = 0; j < 4; ++j) bv[j] = brow[j * 16 + r];

  float* __restrict__ Oc = Out + (size_t)c * (M_PTS * N_DIM);

  for (int mt2 = 0; mt2 < 2; ++mt2) {
    const int m0 = mg * 256 + mt2 * 128;
    const float* __restrict__ xsrc = xrow + (size_t)(m0 + sm) * K_DIM;
    floatx4 acc[4][4] = {};

    for (int kt = 0; kt < 8; ++kt) {
      const int k0 = kt * 32;
      __syncthreads();  // prior-iter As reads done (first: Bt writes visible)
      {
        floatx4 f0 = *(const floatx4*)(xsrc + k0 + 0);
        floatx4 f1 = *(const floatx4*)(xsrc + k0 + 4);
        floatx4 f2 = *(const floatx4*)(xsrc + k0 + 8);
        floatx4 f3 = *(const floatx4*)(xsrc + k0 + 12);
        bf16x8 h0, h1;
#pragma unroll
        for (int v = 0; v < 4; ++v) {
          h0[v]     = cvt_bf16(f0[v]);
          h0[v + 4] = cvt_bf16(f1[v]);
          h1[v]     = cvt_bf16(f2[v]);
          h1[v + 4] = cvt_bf16(f3[v]);
        }
        *(bf16x8*)&adst[0] = h0;  // 16B ds_write
        *(bf16x8*)&adst[8] = h1;
      }
      __syncthreads();  // As visible to all waves

      bf16x8 a[4], b[4];
#pragma unroll
      for (int i = 0; i < 4; ++i)
        a[i] = *(const bf16x8*)&As[(wm * 64 + i * 16 + r) * 32 + kg * 8];
#pragma unroll
      for (int j = 0; j < 4; ++j)
        b[j] = *(const bf16x8*)&Bt[(wn * 64 + j * 16 + r) * BT_STRIDE + k0 + kg * 8];
#pragma unroll
      for (int i = 0; i < 4; ++i)
#pragma unroll
        for (int j = 0; j < 4; ++j)
          acc[i][j] = __builtin_amdgcn_mfma_f32_16x16x32_bf16(a[i], b[j], acc[i][j], 0, 0, 0);
    }

    // ---- epilogue: C/D layout col=lane&15, row=(lane>>4)*4+reg [m89/m91] --
#pragma unroll
    for (int i = 0; i < 4; ++i) {
#pragma unroll
      for (int j = 0; j < 4; ++j) {
        const int col = n0 + wn * 64 + j * 16 + r;
#pragma unroll
        for (int v = 0; v < 4; ++v) {
          const int row = m0 + wm * 64 + i * 16 + kg * 4 + v;
          Oc[(size_t)row * N_DIM + col] = acc[i][j][v] + bv[j];
        }
      }
    }
  }
}

extern "C" void kernel_launch(void* const* d_in, const int* in_sizes, int n_in,
                              void* d_out, int out_size, void* d_ws, size_t ws_size,
                              hipStream_t stream) {
  const float* X   = (const float*)d_in[0];  // x [64,2048,256]
  const float* T   = (const float*)d_in[1];  // t [64]
  const int* MI    = (const int*)d_in[2];    // model_idx [64]
  const float* W   = (const float*)d_in[3];  // W [64,256,256]
  const float* Bb  = (const float*)d_in[4];  // B [32,256]
  float* Out       = (float*)d_out;

  fused_k<<<dim3(1024), dim3(256), 0, stream>>>(X, T, MI, W, Bb, Out);
}